// Round 7
// baseline (237.695 us; speedup 1.0000x reference)
//
#include <hip/hip_runtime.h>

typedef _Float16 f16x8  __attribute__((ext_vector_type(8)));
typedef __fp16   h16x2  __attribute__((ext_vector_type(2)));
typedef float    f32x16 __attribute__((ext_vector_type(16)));

#define NLAYER 5
#define BLOCK  1024
#define WAVES  16
#define ROWS   512           // rows per block-tile (32 per wave)
#define NTILES 2048          // 1048576 / 512
#define GRID   512           // 4 tiles per block; exactly 2 resident blocks/CU

static __device__ __forceinline__ int pkrtz(float a, float b) {
    h16x2 p = __builtin_amdgcn_cvt_pkrtz(a, b);
    return __builtin_bit_cast(int, p);
}

// v_permlane32_swap_b32: one op swaps lane[i]<->lane[i+32] halves of two regs.
static __device__ __forceinline__ void plswap(int& a, int& b) {
    asm("v_permlane32_swap_b32 %0, %1" : "+v"(a), "+v"(b));
}

// ---------------------------------------------------------------------------
// Prep: f32 weights -> fp16 in exact MFMA fragment order:
//   half index = ((((L*2+t)*4+f)*64)+lane)*8 + e
//   value      = W[L][w = 32t + (lane&31)][k = 8*(lane>>5) + 16f + e]
// Same per-lane mapping serves as A-frag (hidden layers) and B-frag (final).
// ---------------------------------------------------------------------------
__global__ __launch_bounds__(256) void prep_weights(
    const float* __restrict__ w_in, const float* __restrict__ w_hid,
    const float* __restrict__ w_out, _Float16* __restrict__ wf)
{
    int idx = blockIdx.x * 256 + threadIdx.x;      // exactly 20480 threads
    int e = idx & 7;
    int l = (idx >> 3) & 63;
    int f = (idx >> 9) & 3;
    int t = (idx >> 11) & 1;
    int L = idx >> 12;
    int w = t * 32 + (l & 31);
    int k = ((l >> 5) << 3) + (f << 4) + e;
    float v;
    if (L == 0)       v = w_in[w * 64 + k];
    else if (L <= 3)  v = w_hid[((L - 1) * 64 + w) * 64 + k];
    else              v = w_out[w * 64 + k];
    wf[idx] = (_Float16)v;
}

// ---------------------------------------------------------------------------
// Fused MLP, max-occupancy version (32 waves/CU).
//  x loads go DIRECTLY to B-fragments (strided; every touched line fully
//  consumed — round 5 proved this pattern is not a limiter). No x-LDS.
//  Only the 40KB weight tile lives in LDS -> 1024-thr blocks, 2 blocks/CU,
//  32 waves/CU. VGPR forced <=64 via __launch_bounds__(1024, 8).
//  Hidden layers: mfma(A=W, B=h), col = batch (layer-invariant);
//    relu -> cvt_pkrtz -> permlane32_swap half-wave exchange.
//  Final layer: swapped operands mfma(A=h, B=W) -> col = feature ->
//    32 dword stores/wave, each two full 128B lines (fully coalesced).
//  Next tile's x register-prefetched under the 5-layer chain.
// ---------------------------------------------------------------------------
__global__ __launch_bounds__(BLOCK, 8) void mlp_kernel(
    const float* __restrict__ x, const f16x8* __restrict__ wfrag_g,
    float* __restrict__ out)
{
    __shared__ f16x8 Wlds[NLAYER * 8 * 64];        // 40960 B (only LDS use)

    const int tid = threadIdx.x;
    {   // weights: linear 40 KB fill, coalesced float4, frag order pre-baked
        const float4* src = (const float4*)wfrag_g;
        float4*       dst = (float4*)Wlds;
#pragma unroll
        for (int i = 0; i < 3; ++i) {
            const int idx = tid + i * BLOCK;
            if (idx < 2560) dst[idx] = src[idx];
        }
    }
    __syncthreads();

    const int lane = tid & 63;
    const int wid  = tid >> 6;
    const int g    = lane >> 5;      // 0/1 : k-half
    const int bl   = lane & 31;      // batch column within wave-tile

    // prologue: first tile's x, direct-to-fragment pattern
    float4 xa[4], xb[4];
    {
        const int row = blockIdx.x * ROWS + wid * 32 + bl;
        const float4* xp = (const float4*)(x + (size_t)row * 64) + 2 * g;
#pragma unroll
        for (int F = 0; F < 4; ++F) { xa[F] = xp[4 * F]; xb[F] = xp[4 * F + 1]; }
    }

    for (int T = blockIdx.x; T < NTILES; T += GRID) {
        // ---- consume prefetched x -> layer-0 B-fragments -------------------
        f16x8 h[4];
#pragma unroll
        for (int F = 0; F < 4; ++F) {
            int4 packed = make_int4(pkrtz(xa[F].x, xa[F].y),
                                    pkrtz(xa[F].z, xa[F].w),
                                    pkrtz(xb[F].x, xb[F].y),
                                    pkrtz(xb[F].z, xb[F].w));
            h[F] = __builtin_bit_cast(f16x8, packed);
        }

        // ---- prefetch next tile's x under the 5-layer chain ----------------
        const int Tn = T + GRID;
        if (Tn < NTILES) {
            const int nrow = Tn * ROWS + wid * 32 + bl;
            const float4* xp = (const float4*)(x + (size_t)nrow * 64) + 2 * g;
#pragma unroll
            for (int F = 0; F < 4; ++F) { xa[F] = xp[4 * F]; xb[F] = xp[4 * F + 1]; }
        }

        const int base = T * ROWS + wid * 32;

        // ---- 4 hidden layers: A=W, B=h (col = batch) -----------------------
#pragma unroll
        for (int L = 0; L < NLAYER - 1; ++L) {
            f32x16 acc0, acc1;
#pragma unroll
            for (int i = 0; i < 16; ++i) { acc0[i] = 0.0f; acc1[i] = 0.0f; }

            const f16x8* WL = &Wlds[L * 8 * 64];
#pragma unroll
            for (int f = 0; f < 4; ++f) {
                acc0 = __builtin_amdgcn_mfma_f32_32x32x16_f16(
                           WL[f * 64 + lane],       h[f], acc0, 0, 0, 0);
                acc1 = __builtin_amdgcn_mfma_f32_32x32x16_f16(
                           WL[(4 + f) * 64 + lane], h[f], acc1, 0, 0, 0);
            }

            // relu + pack: c[t][j] covers w = 32t + 4g + 8*(j>>1) + 2*(j&1)+{0,1}
            int c[2][8];
#pragma unroll
            for (int j = 0; j < 8; ++j) {
                c[0][j] = pkrtz(fmaxf(acc0[2 * j], 0.0f),
                                fmaxf(acc0[2 * j + 1], 0.0f));
                c[1][j] = pkrtz(fmaxf(acc1[2 * j], 0.0f),
                                fmaxf(acc1[2 * j + 1], 0.0f));
            }
            // next-layer B-fragments: frag F dword d holds k = 16F+8g+2d..+1
#pragma unroll
            for (int F = 0; F < 4; ++F) {
                const int t = F >> 1;
                int dw[4];
#pragma unroll
                for (int p = 0; p < 2; ++p) {
                    int xv = c[t][((2 * F) & 3) * 2 + p];
                    int yv = c[t][((2 * F + 1) & 3) * 2 + p];
                    plswap(xv, yv);          // xv={x_lo,y_lo} yv={x_hi,y_hi}
                    dw[p]     = xv;
                    dw[p + 2] = yv;
                }
                int4 packed = make_int4(dw[0], dw[1], dw[2], dw[3]);
                h[F] = __builtin_bit_cast(f16x8, packed);
            }
        }

        // ---- final layer: SWAPPED operands, A=h, B=W (col = feature) -------
        {
            f32x16 acc0, acc1;
#pragma unroll
            for (int i = 0; i < 16; ++i) { acc0[i] = 0.0f; acc1[i] = 0.0f; }

            const f16x8* WL = &Wlds[(NLAYER - 1) * 8 * 64];
#pragma unroll
            for (int f = 0; f < 4; ++f) {
                acc0 = __builtin_amdgcn_mfma_f32_32x32x16_f16(
                           h[f], WL[f * 64 + lane],       acc0, 0, 0, 0);
                acc1 = __builtin_amdgcn_mfma_f32_32x32x16_f16(
                           h[f], WL[(4 + f) * 64 + lane], acc1, 0, 0, 0);
            }

            // lane holds feature bl (acc0) / bl+32 (acc1) of rows
            //   row_local(r,g) = (r&3) + 8*(r>>2) + 4g.
            // Each dword store = 2 full 128B lines (fully coalesced).
            float* o0 = out + (size_t)(base + 4 * g) * 64 + bl;
#pragma unroll
            for (int r = 0; r < 16; ++r) {
                const int off = ((r & 3) + 8 * (r >> 2)) * 64;
                o0[off]      = acc0[r];
                o0[off + 32] = acc1[r];
            }
        }
    }
}

extern "C" void kernel_launch(void* const* d_in, const int* in_sizes, int n_in,
                              void* d_out, int out_size, void* d_ws, size_t ws_size,
                              hipStream_t stream)
{
    const float* x    = (const float*)d_in[0];
    const float* w_in = (const float*)d_in[1];
    const float* w_h  = (const float*)d_in[2];
    const float* w_o  = (const float*)d_in[3];

    _Float16* wf = (_Float16*)d_ws;                 // 20480 halves = 40 KB
    prep_weights<<<80, 256, 0, stream>>>(w_in, w_h, w_o, wf);
    mlp_kernel<<<GRID, BLOCK, 0, stream>>>(x, (const f16x8*)d_ws, (float*)d_out);
}

// Round 9
// 98.605 us; speedup vs baseline: 2.4106x; 2.4106x over previous
//
#include <hip/hip_runtime.h>

typedef _Float16 f16x8  __attribute__((ext_vector_type(8)));
typedef __fp16   h16x2  __attribute__((ext_vector_type(2)));
typedef float    f32x16 __attribute__((ext_vector_type(16)));

#define NLAYER 5
#define BLOCK  512
#define NPAIRS 2048          // pairs of 256-row tiles (512 rows per pair)
#define GRID   1024          // 2 pair-iterations per block

static __device__ __forceinline__ int pkrtz(float a, float b) {
    h16x2 p = __builtin_amdgcn_cvt_pkrtz(a, b);
    return __builtin_bit_cast(int, p);
}

// v_permlane32_swap_b32: one op swaps lane[i]<->lane[i+32] halves of two regs.
static __device__ __forceinline__ void plswap(int& a, int& b) {
    asm("v_permlane32_swap_b32 %0, %1" : "+v"(a), "+v"(b));
}

// ---------------------------------------------------------------------------
// Prep: f32 weights -> fp16 in exact MFMA fragment order:
//   half index = ((((L*2+t)*4+f)*64)+lane)*8 + e
//   value      = W[L][w = 32t + (lane&31)][k = 8*(lane>>5) + 16f + e]
// Same per-lane mapping serves as A-frag (hidden layers) and B-frag (final).
// ---------------------------------------------------------------------------
__global__ __launch_bounds__(256) void prep_weights(
    const float* __restrict__ w_in, const float* __restrict__ w_hid,
    const float* __restrict__ w_out, _Float16* __restrict__ wf)
{
    int idx = blockIdx.x * 256 + threadIdx.x;      // exactly 20480 threads
    int e = idx & 7;
    int l = (idx >> 3) & 63;
    int f = (idx >> 9) & 3;
    int t = (idx >> 11) & 1;
    int L = idx >> 12;
    int w = t * 32 + (l & 31);
    int k = ((l >> 5) << 3) + (f << 4) + e;
    float v;
    if (L == 0)       v = w_in[w * 64 + k];
    else if (L <= 3)  v = w_hid[((L - 1) * 64 + w) * 64 + k];
    else              v = w_out[w * 64 + k];
    wf[idx] = (_Float16)v;
}

// ---------------------------------------------------------------------------
// Fused MLP, dual-tile-stream version (16 waves/CU, no launch-bounds forcing).
//  Per wave per iteration: TWO independent 32-row tiles. Both tiles' 16
//  global_load_dwordx4 issue back-to-back (2x outstanding requests), then
//  the two 5-layer chains run sequentially (VGPR peak ~100, cap 128).
//  Hidden layers: mfma(A=W, B=h), col = batch (layer-invariant);
//    relu -> cvt_pkrtz -> permlane32_swap half-wave exchange.
//  Final layer: swapped operands mfma(A=h, B=W) -> col = feature ->
//    nontemporal dword stores, each two full 128B lines (full-line NT =
//    fillBuffer mode; r4's NT pathology was partial-line scatter).
//  LDS: only the 40KB weight tile.
// ---------------------------------------------------------------------------
__global__ __launch_bounds__(BLOCK, 4) void mlp_kernel(
    const float* __restrict__ x, const f16x8* __restrict__ wfrag_g,
    float* __restrict__ out)
{
    __shared__ f16x8 Wlds[NLAYER * 8 * 64];        // 40960 B (only LDS use)

    const int tid = threadIdx.x;
    {   // weights: linear 40 KB fill, coalesced float4, frag order pre-baked
        const float4* src = (const float4*)wfrag_g;
        float4*       dst = (float4*)Wlds;
#pragma unroll
        for (int i = 0; i < 5; ++i) dst[tid + i * BLOCK] = src[tid + i * BLOCK];
    }
    __syncthreads();

    const int lane = tid & 63;
    const int wid  = tid >> 6;
    const int g    = lane >> 5;      // 0/1 : k-half
    const int bl   = lane & 31;      // batch column within wave-tile

    for (int TP = blockIdx.x; TP < NPAIRS; TP += GRID) {
        const int base0 = TP * 512 + wid * 32;     // stream 0: rows base0..+31
        const int base1 = base0 + 256;             // stream 1: rows base1..+31

        // ---- issue BOTH streams' loads back-to-back (2x requests in flight)
        const float4* xp0 = (const float4*)(x + (size_t)(base0 + bl) * 64) + 2 * g;
        const float4* xp1 = (const float4*)(x + (size_t)(base1 + bl) * 64) + 2 * g;
        float4 a0[4], b0[4], a1[4], b1[4];
#pragma unroll
        for (int F = 0; F < 4; ++F) { a0[F] = xp0[4 * F]; b0[F] = xp0[4 * F + 1]; }
#pragma unroll
        for (int F = 0; F < 4; ++F) { a1[F] = xp1[4 * F]; b1[F] = xp1[4 * F + 1]; }

        // ---- convert both to layer-0 B-fragments (frees the f32 regs) ------
        f16x8 h[2][4];
#pragma unroll
        for (int F = 0; F < 4; ++F) {
            int4 p0 = make_int4(pkrtz(a0[F].x, a0[F].y), pkrtz(a0[F].z, a0[F].w),
                                pkrtz(b0[F].x, b0[F].y), pkrtz(b0[F].z, b0[F].w));
            h[0][F] = __builtin_bit_cast(f16x8, p0);
            int4 p1 = make_int4(pkrtz(a1[F].x, a1[F].y), pkrtz(a1[F].z, a1[F].w),
                                pkrtz(b1[F].x, b1[F].y), pkrtz(b1[F].z, b1[F].w));
            h[1][F] = __builtin_bit_cast(f16x8, p1);
        }

        // ---- two sequential 5-layer chains ---------------------------------
#pragma unroll
        for (int s = 0; s < 2; ++s) {
            const int base = (s == 0) ? base0 : base1;

            // 4 hidden layers: A=W, B=h (col = batch)
#pragma unroll
            for (int L = 0; L < NLAYER - 1; ++L) {
                f32x16 acc0, acc1;
#pragma unroll
                for (int i = 0; i < 16; ++i) { acc0[i] = 0.0f; acc1[i] = 0.0f; }

                const f16x8* WL = &Wlds[L * 8 * 64];
#pragma unroll
                for (int f = 0; f < 4; ++f) {
                    acc0 = __builtin_amdgcn_mfma_f32_32x32x16_f16(
                               WL[f * 64 + lane],       h[s][f], acc0, 0, 0, 0);
                    acc1 = __builtin_amdgcn_mfma_f32_32x32x16_f16(
                               WL[(4 + f) * 64 + lane], h[s][f], acc1, 0, 0, 0);
                }

                // relu + pack: c[t][j] covers w = 32t + 4g + 8*(j>>1) + 2*(j&1)+{0,1}
                int c[2][8];
#pragma unroll
                for (int j = 0; j < 8; ++j) {
                    c[0][j] = pkrtz(fmaxf(acc0[2 * j], 0.0f),
                                    fmaxf(acc0[2 * j + 1], 0.0f));
                    c[1][j] = pkrtz(fmaxf(acc1[2 * j], 0.0f),
                                    fmaxf(acc1[2 * j + 1], 0.0f));
                }
                // next-layer B-fragments: frag F dword d holds k = 16F+8g+2d..+1
#pragma unroll
                for (int F = 0; F < 4; ++F) {
                    const int t = F >> 1;
                    int dw[4];
#pragma unroll
                    for (int p = 0; p < 2; ++p) {
                        int xv = c[t][((2 * F) & 3) * 2 + p];
                        int yv = c[t][((2 * F + 1) & 3) * 2 + p];
                        plswap(xv, yv);      // xv={x_lo,y_lo} yv={x_hi,y_hi}
                        dw[p]     = xv;
                        dw[p + 2] = yv;
                    }
                    int4 packed = make_int4(dw[0], dw[1], dw[2], dw[3]);
                    h[s][F] = __builtin_bit_cast(f16x8, packed);
                }
            }

            // final layer: swapped operands, A=h, B=W (col = feature)
            {
                f32x16 acc0, acc1;
#pragma unroll
                for (int i = 0; i < 16; ++i) { acc0[i] = 0.0f; acc1[i] = 0.0f; }

                const f16x8* WL = &Wlds[(NLAYER - 1) * 8 * 64];
#pragma unroll
                for (int f = 0; f < 4; ++f) {
                    acc0 = __builtin_amdgcn_mfma_f32_32x32x16_f16(
                               h[s][f], WL[f * 64 + lane],       acc0, 0, 0, 0);
                    acc1 = __builtin_amdgcn_mfma_f32_32x32x16_f16(
                               h[s][f], WL[(4 + f) * 64 + lane], acc1, 0, 0, 0);
                }

                // lane holds feature bl (acc0) / bl+32 (acc1) of rows
                //   row_local(r,g) = (r&3) + 8*(r>>2) + 4g.
                // Each NT dword store = 2 full 128B lines (fully coalesced).
                float* o0 = out + (size_t)(base + 4 * g) * 64 + bl;
#pragma unroll
                for (int r = 0; r < 16; ++r) {
                    const int off = ((r & 3) + 8 * (r >> 2)) * 64;
                    __builtin_nontemporal_store(acc0[r], o0 + off);
                    __builtin_nontemporal_store(acc1[r], o0 + off + 32);
                }
            }
        }
    }
}

extern "C" void kernel_launch(void* const* d_in, const int* in_sizes, int n_in,
                              void* d_out, int out_size, void* d_ws, size_t ws_size,
                              hipStream_t stream)
{
    const float* x    = (const float*)d_in[0];
    const float* w_in = (const float*)d_in[1];
    const float* w_h  = (const float*)d_in[2];
    const float* w_o  = (const float*)d_in[3];

    _Float16* wf = (_Float16*)d_ws;                 // 20480 halves = 40 KB
    prep_weights<<<80, 256, 0, stream>>>(w_in, w_h, w_o, wf);
    mlp_kernel<<<GRID, BLOCK, 0, stream>>>(x, (const f16x8*)d_ws, (float*)d_out);
}